// Round 5
// baseline (1004.632 us; speedup 1.0000x reference)
//
#include <hip/hip_runtime.h>
#include <cstddef>

#define NB 4096
#define NT 64
#define NOBS 64
#define NH 64
#define NA 8
#define NS 201

// d_out layout (floats):
//   logits [B,T,A]  @ 0          (2097152)
//   values [T*B]    @ 2097152    (262144)
//   stack  [B,S,H]  @ 2359296    (52690944)
//   ptrs   [B]      @ 55050240   (4096, stored as float)

__global__ void copy_stack_kernel(const float4* __restrict__ src,
                                  float4* __restrict__ dst, int n4) {
    int i = blockIdx.x * blockDim.x + threadIdx.x;
    if (i < n4) dst[i] = src[i];
}

// Broadcast lane l of v to all lanes via SGPR (no LDS round-trip).
__device__ __forceinline__ float rdlane(float v, int l) {
    return __int_as_float(__builtin_amdgcn_readlane(__float_as_int(v), l));
}

__launch_bounds__(256, 2)
__global__ void stacknet_kernel(const float* __restrict__ x,
                                const int* __restrict__ ptrs_in,
                                const float* __restrict__ W1,
                                const float* __restrict__ b1,
                                const float* __restrict__ W2,
                                const float* __restrict__ b2,
                                const float* __restrict__ Ws,
                                const float* __restrict__ bs,
                                const float* __restrict__ Wp,
                                const float* __restrict__ bp,
                                const float* __restrict__ Wv,
                                const float* __restrict__ bv,
                                float* __restrict__ logits_out,
                                float* __restrict__ values_out,
                                float* __restrict__ stack,
                                float* __restrict__ ptrs_out) {
    const int lane = threadIdx.x & 63;
    const int b = (blockIdx.x << 2) + (threadIdx.x >> 6);
    const int aa = lane & 15;                    // head index (0..11 valid)

    // Head weights [a][k], row pad 68 floats (16B-aligned rows for b128).
    // Lanes aa and aa+8 share a bank -> 2-way, which is free (m136).
    __shared__ __align__(16) float shw[16 * 68];
    __shared__ float shb[16];

    for (int i = threadIdx.x; i < 16 * 64; i += 256) {
        int a = i >> 6, k = i & 63;
        float w = 0.0f;
        if (a < 3)        w = Ws[a * 64 + k];
        else if (a < 11)  w = Wp[(a - 3) * 64 + k];
        else if (a == 11) w = Wv[k];
        shw[a * 68 + k] = w;
    }
    if (threadIdx.x < 16) {
        int a = threadIdx.x;
        float bb = 0.0f;
        if (a < 3) bb = bs[a];
        else if (a < 11) bb = bp[a - 3];
        else if (a == 11) bb = bv[0];
        shb[a] = bb;
    }
    __syncthreads();

    // W1 row `lane` (128 floats) and W2 row `lane` (64 floats) in registers
    // (unified VGPR/AGPR file). NOTE: ~40 regs of slack below the 256/wave
    // (2 waves/SIMD) cliff — R3's extra batch slot spilled (FETCH 39MB->2.7GB).
    float w1r[128];
#pragma unroll
    for (int j = 0; j < 32; ++j) {
        float4 tW = ((const float4*)W1)[lane * 32 + j];
        w1r[4*j] = tW.x; w1r[4*j+1] = tW.y; w1r[4*j+2] = tW.z; w1r[4*j+3] = tW.w;
    }
    float w2r[64];
#pragma unroll
    for (int j = 0; j < 16; ++j) {
        float4 tW = ((const float4*)W2)[lane * 16 + j];
        w2r[4*j] = tW.x; w2r[4*j+1] = tW.y; w2r[4*j+2] = tW.z; w2r[4*j+3] = tW.w;
    }
    float b1r = b1[lane];
    float b2r = b2[lane];

    int ptr = ptrs_in[b];
    const float* xb  = x + (size_t)b * NT * NOBS;
    float* stk       = stack + (size_t)b * NS * NH;
    float* lgb       = logits_out + (size_t)b * NT * NA;

    const float* shwa = &shw[aa * 68];
    const float shba = shb[aa];

    float top = stk[ptr * 64 + lane];
    float xv  = xb[lane];                 // x_0, prefetched
    bool pushed = false;
    float pushval = 0.0f;

    for (int t = 0; t < NT; ++t) {
        // ---- Prefetch (all off the critical path):
        //      pop/push candidates for next top, and x_{t+1}.
        int r0 = (ptr > 0) ? (ptr - 1) : 0;
        float c0 = stk[r0 * 64 + lane];
        float c2 = stk[(ptr + 1) * 64 + lane];
        int tn = (t + 1 < NT) ? (t + 1) : t;
        float xn = xb[tn * 64 + lane];

        // ---- h = tanh( dot(W1_row, [x|top]) + b1 ), sequential k (BLAS order).
        //      Broadcast via v_readlane: no LDS round-trip, readlanes issue ahead.
        float acc = 0.0f;
#pragma unroll
        for (int k = 0; k < 64; ++k)
            acc = fmaf(w1r[k], rdlane(xv, k), acc);
#pragma unroll
        for (int k = 0; k < 64; ++k)
            acc = fmaf(w1r[64 + k], rdlane(top, k), acc);
        float h = tanhf(acc + b1r);

        // ---- p = tanh( dot(W2_row, h) + b2 ) ----
        float acc2 = 0.0f;
#pragma unroll
        for (int k = 0; k < 64; ++k)
            acc2 = fmaf(w2r[k], rdlane(h, k), acc2);
        float p = tanhf(acc2 + b2r);

        // ---- 12 head dots, lane aa = head aa, sequential k; weights via b128 LDS ----
        float hacc = 0.0f;
#pragma unroll
        for (int j = 0; j < 16; ++j) {
            float4 w4 = *(const float4*)(shwa + 4*j);
            hacc = fmaf(rdlane(p, 4*j    ), w4.x, hacc);
            hacc = fmaf(rdlane(p, 4*j + 1), w4.y, hacc);
            hacc = fmaf(rdlane(p, 4*j + 2), w4.z, hacc);
            hacc = fmaf(rdlane(p, 4*j + 3), w4.w, hacc);
        }
        float sv = hacc + shba;

        // ---- decision (wave-uniform), softmax mimic, first strict max ----
        float s0 = rdlane(sv, 0), s1 = rdlane(sv, 1), s2 = rdlane(sv, 2);
        float m = fmaxf(fmaxf(s0, s1), s2);
        float e0 = expf(s0 - m), e1 = expf(s1 - m), e2 = expf(s2 - m);
        float S = (e0 + e1) + e2;
        float p0 = e0 / S, p1 = e1 / S, p2 = e2 / S;
        int op = 0; float pm = p0;
        if (p1 > pm) { pm = p1; op = 1; }
        if (p2 > pm) { op = 2; }

        if (op == 2) stk[ptr * 64 + lane] = p;

        // Next top: pop -> c0 (or forwarded pushval if the pop target is the
        // row pushed LAST iteration — store may not have drained); noop -> top;
        // push -> c2 (row above, never written by us this iteration).
        float sel = (op == 0) ? (pushed ? pushval : c0)
                              : ((op == 1) ? top : c2);
        pushed = (op == 2);
        pushval = p;

        int np = ptr + op - 1;
        ptr = (np < 0) ? 0 : np;
        top = sel;
        xv = xn;

        // ---- outputs: lanes 3..10 -> logits, lane 11 -> value ----
        if (lane >= 3 && lane <= 10) {
            lgb[t * NA + (lane - 3)] = sv;
        }
        if (lane == 11) {
            values_out[(size_t)t * NB + b] = sv;
        }
    }
    if (lane == 0) ptrs_out[b] = (float)ptr;
}

extern "C" void kernel_launch(void* const* d_in, const int* in_sizes, int n_in,
                              void* d_out, int out_size, void* d_ws, size_t ws_size,
                              hipStream_t stream) {
    const float* x        = (const float*)d_in[0];
    const float* stack_in = (const float*)d_in[1];
    const int*   ptrs_in  = (const int*)d_in[2];
    const float* W1 = (const float*)d_in[3];
    const float* b1 = (const float*)d_in[4];
    const float* W2 = (const float*)d_in[5];
    const float* b2 = (const float*)d_in[6];
    const float* Ws = (const float*)d_in[7];
    const float* bs = (const float*)d_in[8];
    const float* Wp = (const float*)d_in[9];
    const float* bp = (const float*)d_in[10];
    const float* Wv = (const float*)d_in[11];
    const float* bv = (const float*)d_in[12];

    float* out      = (float*)d_out;
    float* logits   = out;                 // 2097152
    float* values   = out + 2097152;       // 262144
    float* stack    = out + 2359296;       // 52690944
    float* ptrs_out = out + 55050240;      // 4096

    int n4 = 52690944 / 4;                 // 13172736 = 51456 * 256
    copy_stack_kernel<<<51456, 256, 0, stream>>>((const float4*)stack_in,
                                                 (float4*)stack, n4);
    stacknet_kernel<<<1024, 256, 0, stream>>>(x, ptrs_in, W1, b1, W2, b2,
                                              Ws, bs, Wp, bp, Wv, bv,
                                              logits, values, stack, ptrs_out);
}